// Round 1
// baseline (46281.613 us; speedup 1.0000x reference)
//
#include <hip/hip_runtime.h>
#include <cstdint>
#include <cstddef>

#define H 256
#define W 256
#define HW (H*W)
#define BATCH 2
#define CIN_TILE 4

__device__ __forceinline__ float lrelu_f(float v) { return v >= 0.f ? v : 0.1f * v; }

// Direct 3x3 SAME conv. Block: 256 threads, 32x32 spatial tile, each thread 2x2 px,
// CO output channels per block (all CO accumulated per thread).
// Weights read via wave-uniform addresses -> compiler scalarizes to s_load.
// VIRT: source is the virtual concat [feat1(32), feat2(32), corr(169), fr1(16), fr2(16), t=0.5].
// All pointers pre-offset for the batch item; kernel works on a single batch image.
template<int CO, int ACT, bool VIRT>   // ACT: 0=none, 1=lrelu, 2=sigmoid
__global__ __launch_bounds__(256)
void conv3x3_k(const float* __restrict__ src,
               const float* __restrict__ vf1, const float* __restrict__ vf2,
               const float* __restrict__ vcorr, const float* __restrict__ vfr1,
               const float* __restrict__ vfr2,
               const float* __restrict__ wgt, const float* __restrict__ bias,
               float* __restrict__ dst, int Cin, int Cout)
{
  const int coBlk = blockIdx.x;
  const int sp    = blockIdx.y;          // 0..63 (8x8 tiles of 32)
  const int bx = (sp & 7) * 32;
  const int by = (sp >> 3) * 32;
  const int tid = threadIdx.x;
  const int tx = tid & 15, ty = tid >> 4;
  const int co0 = coBlk * CO;

  __shared__ float s_in[CIN_TILE][34][36];

  float acc[CO][2][2];
#pragma unroll
  for (int co = 0; co < CO; ++co) {
    acc[co][0][0] = 0.f; acc[co][0][1] = 0.f;
    acc[co][1][0] = 0.f; acc[co][1][1] = 0.f;
  }

  for (int c0 = 0; c0 < Cin; c0 += CIN_TILE) {
    __syncthreads();
    // ---- stage CIN_TILE channels of the 34x34 halo tile into LDS ----
    const int nst = CIN_TILE * 34 * 34;
    for (int i = tid; i < nst; i += 256) {
      int ci = i / (34 * 34);
      int r  = i - ci * (34 * 34);
      int yy = r / 34;
      int xx = r - yy * 34;
      int gy = by + yy - 1, gx = bx + xx - 1;
      int c = c0 + ci;
      float v = 0.f;
      if (c < Cin && (unsigned)gy < (unsigned)H && (unsigned)gx < (unsigned)W) {
        int off = gy * W + gx;
        if constexpr (VIRT) {
          if (c < 32)        v = vf1[(size_t)c * HW + off];
          else if (c < 64)   v = vf2[(size_t)(c - 32) * HW + off];
          else if (c < 233)  v = vcorr[(size_t)(c - 64) * HW + off];
          else if (c < 249)  v = vfr1[(size_t)(c - 233) * HW + off];
          else if (c < 265)  v = vfr2[(size_t)(c - 249) * HW + off];
          else               v = 0.5f;   // t_map
        } else {
          v = src[(size_t)c * HW + off];
        }
      }
      s_in[ci][yy][xx] = v;
    }
    __syncthreads();

    const int cmax = min(CIN_TILE, Cin - c0);

    auto ci_body = [&](int ci) {
      float win[4][4];
#pragma unroll
      for (int iy = 0; iy < 4; ++iy)
#pragma unroll
        for (int ix = 0; ix < 4; ++ix)
          win[iy][ix] = s_in[ci][2 * ty + iy][2 * tx + ix];

#pragma unroll
      for (int co = 0; co < CO; ++co) {
        int coc = co0 + co;
        if (coc > Cout - 1) coc = Cout - 1;   // clamp: keep weight reads in-bounds & uniform
        const float* wp = wgt + ((size_t)coc * Cin + (c0 + ci)) * 9;
        float w0 = wp[0], w1 = wp[1], w2 = wp[2];
        float w3 = wp[3], w4 = wp[4], w5 = wp[5];
        float w6 = wp[6], w7 = wp[7], w8 = wp[8];
#pragma unroll
        for (int py = 0; py < 2; ++py)
#pragma unroll
          for (int px = 0; px < 2; ++px) {
            float s = acc[co][py][px];
            s += w0 * win[py + 0][px + 0];
            s += w1 * win[py + 0][px + 1];
            s += w2 * win[py + 0][px + 2];
            s += w3 * win[py + 1][px + 0];
            s += w4 * win[py + 1][px + 1];
            s += w5 * win[py + 1][px + 2];
            s += w6 * win[py + 2][px + 0];
            s += w7 * win[py + 2][px + 1];
            s += w8 * win[py + 2][px + 2];
            acc[co][py][px] = s;
          }
      }
    };

    if (cmax == CIN_TILE) {
#pragma unroll
      for (int ci = 0; ci < CIN_TILE; ++ci) ci_body(ci);
    } else {
      for (int ci = 0; ci < cmax; ++ci) ci_body(ci);
    }
  }

  // ---- epilogue: bias + activation + store ----
#pragma unroll
  for (int co = 0; co < CO; ++co) {
    if (co0 + co < Cout) {
      float bv = bias[co0 + co];
#pragma unroll
      for (int py = 0; py < 2; ++py)
#pragma unroll
        for (int px = 0; px < 2; ++px) {
          float v = acc[co][py][px] + bv;
          if (ACT == 1)      v = lrelu_f(v);
          else if (ACT == 2) v = 1.f / (1.f + expf(-v));
          dst[(size_t)(co0 + co) * HW + (size_t)(by + 2 * ty + py) * W + (bx + 2 * tx + px)] = v;
        }
    }
  }
}

// in-place softmax over 25 channels for one batch item: wr = [25][HW]
__global__ __launch_bounds__(256)
void softmax25_k(float* __restrict__ wr)
{
  int p = blockIdx.x * 256 + threadIdx.x;
  if (p >= HW) return;
  float v[25];
  float m = -1e30f;
#pragma unroll
  for (int k = 0; k < 25; ++k) {
    v[k] = wr[(size_t)k * HW + p];
    m = fmaxf(m, v[k]);
  }
  float s = 0.f;
#pragma unroll
  for (int k = 0; k < 25; ++k) {
    v[k] = expf(v[k] - m);
    s += v[k];
  }
  float inv = 1.f / s;
#pragma unroll
  for (int k = 0; k < 25; ++k)
    wr[(size_t)k * HW + p] = v[k] * inv;
}

__device__ __forceinline__ void cubic4(float t, float* w)
{
  const float A_ = -0.75f;
  float t2 = t * t;
  w[1] = ((A_ + 2.f) * t - (A_ + 3.f)) * t2 + 1.f;
  float s = 1.f - t;
  w[2] = ((A_ + 2.f) * s - (A_ + 3.f)) * (s * s) + 1.f;
  float u = t + 1.f;
  w[0] = ((A_ * u - 5.f * A_) * u + 8.f * A_) * u - 4.f * A_;
  float v = 2.f - t;
  w[3] = ((A_ * v - 5.f * A_) * v + 8.f * A_) * v - 4.f * A_;
}

// AdaCoF bicubic sampling for both frames + final blend. Reads offsets/weights/blend
// from d_out regions (already written), writes the output image.
__global__ __launch_bounds__(256)
void adacof_final_k(const float* __restrict__ frame1, const float* __restrict__ frame2,
                    const float* __restrict__ off1, const float* __restrict__ off2,
                    const float* __restrict__ wt1, const float* __restrict__ wt2,
                    const float* __restrict__ blend, float* __restrict__ outp)
{
  int idx = blockIdx.x * 256 + threadIdx.x;
  if (idx >= BATCH * HW) return;
  int b = idx / HW, p = idx - b * HW;
  int y = p / W, x = p - y * W;

  float acc1[3] = {0.f, 0.f, 0.f};
  float acc2[3] = {0.f, 0.f, 0.f};

  auto samp = [&](const float* __restrict__ img, const float* __restrict__ off,
                  const float* __restrict__ wts, float* acc) {
    for (int k = 0; k < 25; ++k) {
      float dx = off[((size_t)b * 50 + 2 * k) * HW + p];
      float dy = off[((size_t)b * 50 + 2 * k + 1) * HW + p];
      float wk = wts[((size_t)b * 25 + k) * HW + p];
      float sx = (float)x + dx, sy = (float)y + dy;
      float x0 = floorf(sx), y0 = floorf(sy);
      float tx = sx - x0, ty = sy - y0;
      float wx[4], wy[4];
      cubic4(tx, wx);
      cubic4(ty, wy);
      int xi[4], yi[4];
#pragma unroll
      for (int i = 0; i < 4; ++i) {
        xi[i] = (int)fminf(fmaxf(x0 + (float)(i - 1), 0.f), (float)(W - 1));
        yi[i] = (int)fminf(fmaxf(y0 + (float)(i - 1), 0.f), (float)(H - 1));
      }
      const float* c0 = img + ((size_t)b * 3 + 0) * HW;
      const float* c1 = img + ((size_t)b * 3 + 1) * HW;
      const float* c2 = img + ((size_t)b * 3 + 2) * HW;
#pragma unroll
      for (int i = 0; i < 4; ++i) {
#pragma unroll
        for (int j = 0; j < 4; ++j) {
          float wf = wy[i] * wx[j] * wk;
          int q = yi[i] * W + xi[j];
          acc[0] += c0[q] * wf;
          acc[1] += c1[q] * wf;
          acc[2] += c2[q] * wf;
        }
      }
    }
  };

  samp(frame1, off1, wt1, acc1);
  samp(frame2, off2, wt2, acc2);

  float bl = blend[(size_t)b * HW + p];
#pragma unroll
  for (int c = 0; c < 3; ++c)
    outp[((size_t)b * 3 + c) * HW + p] = bl * acc1[c] + (1.f - bl) * acc2[c];
}

extern "C" void kernel_launch(void* const* d_in, const int* in_sizes, int n_in,
                              void* d_out, int out_size, void* d_ws, size_t ws_size,
                              hipStream_t stream)
{
  const float* frame1 = (const float*)d_in[0];
  const float* frame2 = (const float*)d_in[1];
  const float* feat1  = (const float*)d_in[2];
  const float* feat2  = (const float*)d_in[3];
  const float* corr   = (const float*)d_in[4];
  const float* fr_w1  = (const float*)d_in[5];
  const float* fr_b1  = (const float*)d_in[6];
  const float* fr_w2  = (const float*)d_in[7];
  const float* fr_b2  = (const float*)d_in[8];

  const float* kw1[2] = {(const float*)d_in[9],  (const float*)d_in[19]};
  const float* kb1[2] = {(const float*)d_in[10], (const float*)d_in[20]};
  const float* kw2[2] = {(const float*)d_in[11], (const float*)d_in[21]};
  const float* kb2[2] = {(const float*)d_in[12], (const float*)d_in[22]};
  const float* kw3[2] = {(const float*)d_in[13], (const float*)d_in[23]};
  const float* kb3[2] = {(const float*)d_in[14], (const float*)d_in[24]};
  const float* kow[2] = {(const float*)d_in[15], (const float*)d_in[25]};
  const float* kob[2] = {(const float*)d_in[16], (const float*)d_in[26]};
  const float* kww[2] = {(const float*)d_in[17], (const float*)d_in[27]};
  const float* kwb[2] = {(const float*)d_in[18], (const float*)d_in[28]};

  const float* bl_w1 = (const float*)d_in[29];
  const float* bl_b1 = (const float*)d_in[30];
  const float* bl_w2 = (const float*)d_in[31];
  const float* bl_b2 = (const float*)d_in[32];

  float* out = (float*)d_out;
  float* o_out   = out;                                   // [2][3][H][W]
  float* o_blend = o_out   + (size_t)BATCH * 3 * HW;      // [2][1][H][W]
  float* o_off1  = o_blend + (size_t)BATCH * 1 * HW;      // [2][50][H][W]
  float* o_off2  = o_off1  + (size_t)BATCH * 50 * HW;
  float* o_w1    = o_off2  + (size_t)BATCH * 50 * HW;     // [2][25][H][W]
  float* o_w2    = o_w1    + (size_t)BATCH * 25 * HW;

  // workspace (per-batch-item buffers): 3*16ch + 2*256ch = ~147 MB
  float* ws     = (float*)d_ws;
  float* fr_tmp = ws;                                   // [16][HW]
  float* fr1b   = fr_tmp + (size_t)16 * HW;             // [16][HW]
  float* fr2b   = fr1b   + (size_t)16 * HW;             // [16][HW]
  float* bufA   = fr2b   + (size_t)16 * HW;             // [256][HW]
  float* bufB   = bufA   + (size_t)256 * HW;            // [256][HW]

  const float* nul = nullptr;
  dim3 blk(256);

  for (int b = 0; b < BATCH; ++b) {
    const float* f1b = frame1 + (size_t)b * 3 * HW;
    const float* f2b = frame2 + (size_t)b * 3 * HW;
    const float* fe1 = feat1  + (size_t)b * 32 * HW;
    const float* fe2 = feat2  + (size_t)b * 32 * HW;
    const float* crb = corr   + (size_t)b * 169 * HW;

    // frame feature extractor (shared weights) for both frames
    conv3x3_k<16, 1, false><<<dim3(1, 64, 1), blk, 0, stream>>>(
        f1b, nul, nul, nul, nul, nul, fr_w1, fr_b1, fr_tmp, 3, 16);
    conv3x3_k<16, 1, false><<<dim3(1, 64, 1), blk, 0, stream>>>(
        fr_tmp, nul, nul, nul, nul, nul, fr_w2, fr_b2, fr1b, 16, 16);
    conv3x3_k<16, 1, false><<<dim3(1, 64, 1), blk, 0, stream>>>(
        f2b, nul, nul, nul, nul, nul, fr_w1, fr_b1, fr_tmp, 3, 16);
    conv3x3_k<16, 1, false><<<dim3(1, 64, 1), blk, 0, stream>>>(
        fr_tmp, nul, nul, nul, nul, nul, fr_w2, fr_b2, fr2b, 16, 16);

    // two kernel-prediction heads
    for (int p = 0; p < 2; ++p) {
      float* ooff = (p ? o_off2 : o_off1) + (size_t)b * 50 * HW;
      float* oww  = (p ? o_w2   : o_w1)   + (size_t)b * 25 * HW;

      conv3x3_k<16, 1, true><<<dim3(16, 64, 1), blk, 0, stream>>>(
          nul, fe1, fe2, crb, fr1b, fr2b, kw1[p], kb1[p], bufA, 266, 256);
      conv3x3_k<16, 1, false><<<dim3(16, 64, 1), blk, 0, stream>>>(
          bufA, nul, nul, nul, nul, nul, kw2[p], kb2[p], bufB, 256, 256);
      conv3x3_k<16, 1, false><<<dim3(8, 64, 1), blk, 0, stream>>>(
          bufB, nul, nul, nul, nul, nul, kw3[p], kb3[p], bufA, 256, 128);
      conv3x3_k<16, 0, false><<<dim3(4, 64, 1), blk, 0, stream>>>(
          bufA, nul, nul, nul, nul, nul, kow[p], kob[p], ooff, 128, 50);
      conv3x3_k<16, 0, false><<<dim3(2, 64, 1), blk, 0, stream>>>(
          bufA, nul, nul, nul, nul, nul, kww[p], kwb[p], oww, 128, 25);
      softmax25_k<<<dim3(HW / 256), blk, 0, stream>>>(oww);
    }

    // blend branch
    conv3x3_k<16, 1, true><<<dim3(4, 64, 1), blk, 0, stream>>>(
        nul, fe1, fe2, crb, fr1b, fr2b, bl_w1, bl_b1, bufB, 266, 64);
    conv3x3_k<1, 2, false><<<dim3(1, 64, 1), blk, 0, stream>>>(
        bufB, nul, nul, nul, nul, nul, bl_w2, bl_b2, o_blend + (size_t)b * HW, 64, 1);
  }

  // AdaCoF sampling for both frames + final blend
  adacof_final_k<<<dim3((BATCH * HW + 255) / 256), blk, 0, stream>>>(
      frame1, frame2, o_off1, o_off2, o_w1, o_w2, o_blend, o_out);
}

// Round 2
// 1484.370 us; speedup vs baseline: 31.1793x; 31.1793x over previous
//
#include <hip/hip_runtime.h>
#include <cstdint>
#include <cstddef>

#define H 256
#define W 256
#define HW (H*W)
#define BATCH 2
#define CIN_TILE 4

typedef __bf16 bf16x8 __attribute__((ext_vector_type(8)));
typedef float f32x4 __attribute__((ext_vector_type(4)));
typedef __attribute__((address_space(1))) uint32_t gu32_t;
typedef __attribute__((address_space(3))) uint32_t lu32_t;

__device__ __forceinline__ void async16(const void* g, void* l) {
  __builtin_amdgcn_global_load_lds((const gu32_t*)g, (lu32_t*)l, 16, 0, 0);
}

__device__ __forceinline__ ushort f2bf(float f) {
  uint u = __float_as_uint(f);
  return (ushort)((u + 0x7FFFu + ((u >> 16) & 1u)) >> 16);
}
__device__ __forceinline__ float lrelu_f(float v) { return v >= 0.f ? v : 0.1f * v; }

// ---------------------------------------------------------------------------
// MFMA implicit-GEMM 3x3 SAME conv.  Activations NHWC bf16 (stride Cin).
// Block: 256 thr (4 waves), tile 64 co x (32x8) px.  Weights prepped
// [co][tap][Cin_pad] bf16.  EPI 0: bf16 NHWC + lrelu.  EPI 1: head planar
// fp32 (co<50 -> offsets, 50..74 -> weights logits).
// ---------------------------------------------------------------------------
template<int EPI>
__global__ __launch_bounds__(256) void convmm_k(
    const ushort* __restrict__ act, const ushort* __restrict__ wgt,
    const float* __restrict__ bias, ushort* __restrict__ dstb,
    float* __restrict__ dsto, float* __restrict__ dstw,
    const ushort* __restrict__ zpage, int Cin, int CoutS)
{
  __shared__ __align__(16) ushort s_w[2304 * 8];   // [tap][k16][co64][8ci] = 36 KB
  __shared__ __align__(16) ushort s_b[1536 * 8];   // [k16][384 px][8ci]    = 24 KB

  const int tid = threadIdx.x;
  const int sp = blockIdx.x;
  const int bx = (sp & 7) * 32, by = (sp >> 3) * 8;
  const int co0 = blockIdx.y * 64;
  const int wv = tid >> 6, lane = tid & 63;
  const int c = lane & 15, kq = lane >> 4;
  const int oy = wv * 2;

  // precomputed staging source offsets (elements); chunk adds c0
  int wsrc[9];
#pragma unroll
  for (int it = 0; it < 9; ++it) {
    int i = tid + it * 256;
    int co = i & 63, tk = i >> 6, tap = tk >> 2, kg = tk & 3;
    wsrc[it] = ((co0 + co) * 9 + tap) * Cin + kg * 8;
  }
  int bsrc[6];
#pragma unroll
  for (int it = 0; it < 6; ++it) {
    int i = tid + it * 256;
    int kg = i / 384, px = i - kg * 384;
    int row = px / 34, xx = px - row * 34;
    int gy = by + row - 1, gx = bx + xx - 1;
    bool ok = (px < 340) && ((unsigned)gy < (unsigned)H) && ((unsigned)gx < (unsigned)W);
    bsrc[it] = ok ? ((gy * W + gx) * Cin + kg * 8) : -1;
  }

  f32x4 acc[4][4];
#pragma unroll
  for (int a = 0; a < 4; ++a)
#pragma unroll
    for (int b2 = 0; b2 < 4; ++b2) acc[a][b2] = (f32x4){0.f, 0.f, 0.f, 0.f};

  const int nch = Cin >> 5;
  for (int ch = 0; ch < nch; ++ch) {
    const int c0 = ch << 5;
    __syncthreads();
#pragma unroll
    for (int it = 0; it < 9; ++it)
      async16(wgt + wsrc[it] + c0, &s_w[(size_t)(tid + it * 256) * 8]);
#pragma unroll
    for (int it = 0; it < 6; ++it) {
      const ushort* g = (bsrc[it] < 0) ? zpage : (act + bsrc[it] + c0);
      async16(g, &s_b[(size_t)(tid + it * 256) * 8]);
    }
    __syncthreads();

#pragma unroll
    for (int t = 0; t < 9; ++t) {
      const int dy = t / 3 - 1, dx = t % 3 - 1;
      bf16x8 B[4];
#pragma unroll
      for (int pf = 0; pf < 4; ++pf) {
        int p = (oy + (pf >> 1) + dy + 1) * 34 + (pf & 1) * 16 + dx + 1 + c;
        B[pf] = *(const bf16x8*)&s_b[(size_t)(kq * 384 + p) * 8];
      }
#pragma unroll
      for (int cf = 0; cf < 4; ++cf) {
        bf16x8 A = *(const bf16x8*)&s_w[(size_t)((t * 4 + kq) * 64 + cf * 16 + c) * 8];
#pragma unroll
        for (int pf = 0; pf < 4; ++pf)
          acc[cf][pf] = __builtin_amdgcn_mfma_f32_16x16x32_bf16(A, B[pf], acc[cf][pf], 0, 0, 0);
      }
    }
  }

  // epilogue: D col=lane&15 (pixel), row=(lane>>4)*4+reg (co)
  const int r4 = kq * 4;
#pragma unroll
  for (int cf = 0; cf < 4; ++cf) {
    int cob = co0 + cf * 16 + r4;
#pragma unroll
    for (int pf = 0; pf < 4; ++pf) {
      int gx2 = bx + (pf & 1) * 16 + c;
      int gy2 = by + oy + (pf >> 1);
      int gpix = gy2 * W + gx2;
      f32x4 v = acc[cf][pf];
      const float4 bv = *(const float4*)&bias[cob];
      if constexpr (EPI == 0) {
        ushort4 ov;
        float f0 = lrelu_f(v[0] + bv.x);
        float f1 = lrelu_f(v[1] + bv.y);
        float f2 = lrelu_f(v[2] + bv.z);
        float f3 = lrelu_f(v[3] + bv.w);
        ov.x = f2bf(f0); ov.y = f2bf(f1); ov.z = f2bf(f2); ov.w = f2bf(f3);
        *(ushort4*)&dstb[(size_t)gpix * CoutS + cob] = ov;
      } else {
        const float* bvp = &bv.x;
#pragma unroll
        for (int r = 0; r < 4; ++r) {
          int coa = cob + r;
          if (coa < 75) {
            float f = v[r] + bvp[r];
            if (coa < 50) dsto[(size_t)coa * HW + gpix] = f;
            else          dstw[(size_t)(coa - 50) * HW + gpix] = f;
          }
        }
      }
    }
  }
}

// ---------------------------------------------------------------------------
// Small fp32 extractor conv (planar), batched over z = frame*2 + batch
// ---------------------------------------------------------------------------
template<int CIN>
__global__ __launch_bounds__(256) void conv_fr_k(
    const float* __restrict__ sA, const float* __restrict__ sB, int mode,
    const float* __restrict__ wgt, const float* __restrict__ bias,
    float* __restrict__ dst)
{
  const int z = blockIdx.y;
  const float* src = (mode == 0)
      ? (((z >> 1) ? sB : sA) + (size_t)(z & 1) * 3 * HW)
      : (sA + (size_t)z * 16 * HW);
  float* out = dst + (size_t)z * 16 * HW;

  const int sp = blockIdx.x;
  const int bx = (sp & 7) * 32, by = (sp >> 3) * 32;
  const int tid = threadIdx.x;
  const int tx = tid & 15, ty = tid >> 4;

  __shared__ float s_in[CIN_TILE][34][36];
  float acc[16][2][2];
#pragma unroll
  for (int co = 0; co < 16; ++co) {
    acc[co][0][0] = 0.f; acc[co][0][1] = 0.f;
    acc[co][1][0] = 0.f; acc[co][1][1] = 0.f;
  }

  for (int c0 = 0; c0 < CIN; c0 += CIN_TILE) {
    __syncthreads();
    const int nst = CIN_TILE * 34 * 34;
    for (int i = tid; i < nst; i += 256) {
      int ci = i / (34 * 34);
      int r = i - ci * (34 * 34);
      int yy = r / 34;
      int xx = r - yy * 34;
      int gy = by + yy - 1, gx = bx + xx - 1;
      int cc = c0 + ci;
      float v = 0.f;
      if (cc < CIN && (unsigned)gy < (unsigned)H && (unsigned)gx < (unsigned)W)
        v = src[(size_t)cc * HW + gy * W + gx];
      s_in[ci][yy][xx] = v;
    }
    __syncthreads();

    const int cmax = (CIN - c0 < CIN_TILE) ? (CIN - c0) : CIN_TILE;
    for (int ci = 0; ci < cmax; ++ci) {
      float win[4][4];
#pragma unroll
      for (int iy = 0; iy < 4; ++iy)
#pragma unroll
        for (int ix = 0; ix < 4; ++ix)
          win[iy][ix] = s_in[ci][2 * ty + iy][2 * tx + ix];
#pragma unroll
      for (int co = 0; co < 16; ++co) {
        const float* wp = wgt + ((size_t)co * CIN + (c0 + ci)) * 9;
        float w0 = wp[0], w1 = wp[1], w2 = wp[2];
        float w3 = wp[3], w4 = wp[4], w5 = wp[5];
        float w6 = wp[6], w7 = wp[7], w8 = wp[8];
#pragma unroll
        for (int py = 0; py < 2; ++py)
#pragma unroll
          for (int px = 0; px < 2; ++px) {
            float s = acc[co][py][px];
            s += w0 * win[py + 0][px + 0];
            s += w1 * win[py + 0][px + 1];
            s += w2 * win[py + 0][px + 2];
            s += w3 * win[py + 1][px + 0];
            s += w4 * win[py + 1][px + 1];
            s += w5 * win[py + 1][px + 2];
            s += w6 * win[py + 2][px + 0];
            s += w7 * win[py + 2][px + 1];
            s += w8 * win[py + 2][px + 2];
            acc[co][py][px] = s;
          }
      }
    }
  }
#pragma unroll
  for (int co = 0; co < 16; ++co) {
    float bv = bias[co];
#pragma unroll
    for (int py = 0; py < 2; ++py)
#pragma unroll
      for (int px = 0; px < 2; ++px)
        out[(size_t)co * HW + (size_t)(by + 2 * ty + py) * W + (bx + 2 * tx + px)] =
            lrelu_f(acc[co][py][px] + bv);
  }
}

// ---------------------------------------------------------------------------
// Build combined NHWC bf16 [HW][288] for batch item b
// ---------------------------------------------------------------------------
__global__ __launch_bounds__(256) void pack_k(
    const float* __restrict__ feat1, const float* __restrict__ feat2,
    const float* __restrict__ corr, const float* __restrict__ fr,
    ushort* __restrict__ comb, int b)
{
  int gid = blockIdx.x * 256 + threadIdx.x;   // over 9*HW
  int chunk = gid / HW;
  int p = gid - chunk * HW;
  int c0 = chunk * 32;

  uint u[16];
#pragma unroll
  for (int j = 0; j < 32; j += 2) {
    float f[2];
#pragma unroll
    for (int q = 0; q < 2; ++q) {
      int cc = c0 + j + q;
      float v;
      if (cc < 32)       v = feat1[(size_t)(b * 32 + cc) * HW + p];
      else if (cc < 64)  v = feat2[(size_t)(b * 32 + cc - 32) * HW + p];
      else if (cc < 233) v = corr[(size_t)(b * 169 + cc - 64) * HW + p];
      else if (cc < 249) v = fr[(size_t)(b * 16 + (cc - 233)) * HW + p];
      else if (cc < 265) v = fr[(size_t)((2 + b) * 16 + (cc - 249)) * HW + p];
      else if (cc == 265) v = 0.5f;
      else               v = 0.f;
      f[q] = v;
    }
    u[j >> 1] = (uint)f2bf(f[0]) | ((uint)f2bf(f[1]) << 16);
  }
  uint4* dst = (uint4*)&comb[(size_t)p * 288 + c0];
#pragma unroll
  for (int q = 0; q < 4; ++q) {
    uint4 t;
    t.x = u[q * 4 + 0]; t.y = u[q * 4 + 1]; t.z = u[q * 4 + 2]; t.w = u[q * 4 + 3];
    dst[q] = t;
  }
}

// weight prep: [O][I][3][3] fp32 -> [O][9][Ipad] bf16
__global__ __launch_bounds__(256) void prep_w_k(
    const float* __restrict__ src, ushort* __restrict__ dst, int O, int I, int Ipad)
{
  int idx = blockIdx.x * 256 + threadIdx.x;
  int tot = O * 9 * Ipad;
  if (idx >= tot) return;
  int i = idx % Ipad;
  int r = idx / Ipad;
  int tap = r % 9;
  int o = r / 9;
  float v = (i < I) ? src[((size_t)o * I + i) * 9 + tap] : 0.f;
  dst[idx] = f2bf(v);
}

__global__ __launch_bounds__(256) void zfill_k(ushort* __restrict__ dst, int n)
{
  int idx = blockIdx.x * 256 + threadIdx.x;
  if (idx < n) dst[idx] = 0;
}

__global__ __launch_bounds__(128) void hbias_k(
    const float* __restrict__ ob, const float* __restrict__ wb, float* __restrict__ out)
{
  int i = threadIdx.x;
  float v = 0.f;
  if (i < 50) v = ob[i];
  else if (i < 75) v = wb[i - 50];
  out[i] = v;
}

// blend second conv: NHWC bf16 64ch -> sigmoid fp32 planar
__global__ __launch_bounds__(256) void blend2_k(
    const ushort* __restrict__ actD, const float* __restrict__ wgt,
    const float* __restrict__ b2, float* __restrict__ outp)
{
  int p = blockIdx.x * 256 + threadIdx.x;
  int y = p >> 8, x = p & 255;
  float acc = b2[0];
  for (int dy = -1; dy <= 1; ++dy) {
    int gy = y + dy;
    if ((unsigned)gy >= (unsigned)H) continue;
    for (int dx = -1; dx <= 1; ++dx) {
      int gx = x + dx;
      if ((unsigned)gx >= (unsigned)W) continue;
      int tap = (dy + 1) * 3 + (dx + 1);
      const ushort* rowp = actD + (size_t)(gy * W + gx) * 64;
#pragma unroll
      for (int c8 = 0; c8 < 8; ++c8) {
        uint4 v = *(const uint4*)&rowp[c8 * 8];
        const uint* vv = &v.x;
#pragma unroll
        for (int q = 0; q < 4; ++q) {
          float f0 = __uint_as_float(vv[q] << 16);
          float f1 = __uint_as_float(vv[q] & 0xFFFF0000u);
          int ci = c8 * 8 + q * 2;
          acc += f0 * wgt[ci * 9 + tap];
          acc += f1 * wgt[(ci + 1) * 9 + tap];
        }
      }
    }
  }
  outp[p] = 1.f / (1.f + expf(-acc));
}

// in-place softmax over 25 channels: wr = [25][HW]
__global__ __launch_bounds__(256) void softmax25_k(float* __restrict__ wr)
{
  int p = blockIdx.x * 256 + threadIdx.x;
  if (p >= HW) return;
  float v[25];
  float m = -1e30f;
#pragma unroll
  for (int k = 0; k < 25; ++k) {
    v[k] = wr[(size_t)k * HW + p];
    m = fmaxf(m, v[k]);
  }
  float s = 0.f;
#pragma unroll
  for (int k = 0; k < 25; ++k) {
    v[k] = expf(v[k] - m);
    s += v[k];
  }
  float inv = 1.f / s;
#pragma unroll
  for (int k = 0; k < 25; ++k)
    wr[(size_t)k * HW + p] = v[k] * inv;
}

__device__ __forceinline__ void cubic4(float t, float* cw)
{
  const float A_ = -0.75f;
  float t2 = t * t;
  cw[1] = ((A_ + 2.f) * t - (A_ + 3.f)) * t2 + 1.f;
  float s = 1.f - t;
  cw[2] = ((A_ + 2.f) * s - (A_ + 3.f)) * (s * s) + 1.f;
  float u = t + 1.f;
  cw[0] = ((A_ * u - 5.f * A_) * u + 8.f * A_) * u - 4.f * A_;
  float v = 2.f - t;
  cw[3] = ((A_ * v - 5.f * A_) * v + 8.f * A_) * v - 4.f * A_;
}

__global__ __launch_bounds__(256) void adacof_final_k(
    const float* __restrict__ frame1, const float* __restrict__ frame2,
    const float* __restrict__ off1, const float* __restrict__ off2,
    const float* __restrict__ wt1, const float* __restrict__ wt2,
    const float* __restrict__ blend, float* __restrict__ outp)
{
  int idx = blockIdx.x * 256 + threadIdx.x;
  if (idx >= BATCH * HW) return;
  int b = idx / HW, p = idx - b * HW;
  int y = p / W, x = p - y * W;

  float acc1[3] = {0.f, 0.f, 0.f};
  float acc2[3] = {0.f, 0.f, 0.f};

  auto samp = [&](const float* __restrict__ img, const float* __restrict__ off,
                  const float* __restrict__ wts, float* acc) {
    for (int k = 0; k < 25; ++k) {
      float dx = off[((size_t)b * 50 + 2 * k) * HW + p];
      float dy = off[((size_t)b * 50 + 2 * k + 1) * HW + p];
      float wk = wts[((size_t)b * 25 + k) * HW + p];
      float sx = (float)x + dx, sy = (float)y + dy;
      float x0 = floorf(sx), y0 = floorf(sy);
      float tx = sx - x0, ty = sy - y0;
      float wx[4], wy[4];
      cubic4(tx, wx);
      cubic4(ty, wy);
      int xi[4], yi[4];
#pragma unroll
      for (int i = 0; i < 4; ++i) {
        xi[i] = (int)fminf(fmaxf(x0 + (float)(i - 1), 0.f), (float)(W - 1));
        yi[i] = (int)fminf(fmaxf(y0 + (float)(i - 1), 0.f), (float)(H - 1));
      }
      const float* c0 = img + ((size_t)b * 3 + 0) * HW;
      const float* c1 = img + ((size_t)b * 3 + 1) * HW;
      const float* c2 = img + ((size_t)b * 3 + 2) * HW;
#pragma unroll
      for (int i = 0; i < 4; ++i) {
#pragma unroll
        for (int j = 0; j < 4; ++j) {
          float wf = wy[i] * wx[j] * wk;
          int q = yi[i] * W + xi[j];
          acc[0] += c0[q] * wf;
          acc[1] += c1[q] * wf;
          acc[2] += c2[q] * wf;
        }
      }
    }
  };

  samp(frame1, off1, wt1, acc1);
  samp(frame2, off2, wt2, acc2);

  float bl = blend[(size_t)b * HW + p];
#pragma unroll
  for (int ci = 0; ci < 3; ++ci)
    outp[((size_t)b * 3 + ci) * HW + p] = bl * acc1[ci] + (1.f - bl) * acc2[ci];
}

// ---------------------------------------------------------------------------
extern "C" void kernel_launch(void* const* d_in, const int* in_sizes, int n_in,
                              void* d_out, int out_size, void* d_ws, size_t ws_size,
                              hipStream_t stream)
{
  const float* frame1 = (const float*)d_in[0];
  const float* frame2 = (const float*)d_in[1];
  const float* feat1  = (const float*)d_in[2];
  const float* feat2  = (const float*)d_in[3];
  const float* corr   = (const float*)d_in[4];
  const float* fr_w1  = (const float*)d_in[5];
  const float* fr_b1  = (const float*)d_in[6];
  const float* fr_w2  = (const float*)d_in[7];
  const float* fr_b2  = (const float*)d_in[8];

  const float* kw1[2] = {(const float*)d_in[9],  (const float*)d_in[19]};
  const float* kb1[2] = {(const float*)d_in[10], (const float*)d_in[20]};
  const float* kw2[2] = {(const float*)d_in[11], (const float*)d_in[21]};
  const float* kb2[2] = {(const float*)d_in[12], (const float*)d_in[22]};
  const float* kw3[2] = {(const float*)d_in[13], (const float*)d_in[23]};
  const float* kb3[2] = {(const float*)d_in[14], (const float*)d_in[24]};
  const float* kow[2] = {(const float*)d_in[15], (const float*)d_in[25]};
  const float* kob[2] = {(const float*)d_in[16], (const float*)d_in[26]};
  const float* kww[2] = {(const float*)d_in[17], (const float*)d_in[27]};
  const float* kwb[2] = {(const float*)d_in[18], (const float*)d_in[28]};

  const float* bl_w1 = (const float*)d_in[29];
  const float* bl_b1 = (const float*)d_in[30];
  const float* bl_w2 = (const float*)d_in[31];
  const float* bl_b2 = (const float*)d_in[32];

  float* out = (float*)d_out;
  float* o_out   = out;
  float* o_blend = o_out   + (size_t)BATCH * 3 * HW;
  float* o_off1  = o_blend + (size_t)BATCH * 1 * HW;
  float* o_off2  = o_off1  + (size_t)BATCH * 50 * HW;
  float* o_w1    = o_off2  + (size_t)BATCH * 50 * HW;
  float* o_w2    = o_w1    + (size_t)BATCH * 25 * HW;

  // ---- workspace layout ----
  size_t off = 0;
  char* wsb = (char*)d_ws;
  auto alloc = [&](size_t bytes) -> void* {
    void* pp = wsb + off;
    off += (bytes + 255) & ~(size_t)255;
    return pp;
  };
  ushort* zpage   = (ushort*)alloc(512);
  ushort* wp1[2]  = {(ushort*)alloc((size_t)256 * 9 * 288 * 2), (ushort*)alloc((size_t)256 * 9 * 288 * 2)};
  ushort* wp2[2]  = {(ushort*)alloc((size_t)256 * 9 * 256 * 2), (ushort*)alloc((size_t)256 * 9 * 256 * 2)};
  ushort* wp3[2]  = {(ushort*)alloc((size_t)128 * 9 * 256 * 2), (ushort*)alloc((size_t)128 * 9 * 256 * 2)};
  ushort* wph[2]  = {(ushort*)alloc((size_t)128 * 9 * 128 * 2), (ushort*)alloc((size_t)128 * 9 * 128 * 2)};
  ushort* wpb     = (ushort*)alloc((size_t)64 * 9 * 288 * 2);
  float*  hbias[2] = {(float*)alloc(128 * 4), (float*)alloc(128 * 4)};
  float*  tmp4    = (float*)alloc((size_t)4 * 16 * HW * 4);
  float*  frbuf   = (float*)alloc((size_t)4 * 16 * HW * 4);
  ushort* comb    = (ushort*)alloc((size_t)HW * 288 * 2);
  ushort* actA    = (ushort*)alloc((size_t)HW * 256 * 2);
  ushort* actB    = (ushort*)alloc((size_t)HW * 256 * 2);
  ushort* actC    = actA;   // reuse after conv2 consumed actA
  ushort* actD    = actB;   // reuse after heads consumed actB

  dim3 blk(256);

  // ---- one-time prep (runs every launch; deterministic) ----
  hipMemsetAsync(zpage, 0, 512, stream);
  for (int p = 0; p < 2; ++p) {
    prep_w_k<<<dim3((256 * 9 * 288 + 255) / 256), blk, 0, stream>>>(kw1[p], wp1[p], 256, 266, 288);
    prep_w_k<<<dim3((256 * 9 * 256 + 255) / 256), blk, 0, stream>>>(kw2[p], wp2[p], 256, 256, 256);
    prep_w_k<<<dim3((128 * 9 * 256 + 255) / 256), blk, 0, stream>>>(kw3[p], wp3[p], 128, 256, 256);
    prep_w_k<<<dim3((50 * 9 * 128 + 255) / 256), blk, 0, stream>>>(kow[p], wph[p], 50, 128, 128);
    prep_w_k<<<dim3((25 * 9 * 128 + 255) / 256), blk, 0, stream>>>(kww[p], wph[p] + (size_t)50 * 9 * 128, 25, 128, 128);
    zfill_k<<<dim3((53 * 9 * 128 + 255) / 256), blk, 0, stream>>>(wph[p] + (size_t)75 * 9 * 128, 53 * 9 * 128);
    hbias_k<<<dim3(1), dim3(128), 0, stream>>>(kob[p], kwb[p], hbias[p]);
  }
  prep_w_k<<<dim3((64 * 9 * 288 + 255) / 256), blk, 0, stream>>>(bl_w1, wpb, 64, 266, 288);

  // ---- frame extractor (fp32, batched z = frame*2 + batch) ----
  conv_fr_k<3><<<dim3(64, 4), blk, 0, stream>>>(frame1, frame2, 0, fr_w1, fr_b1, tmp4);
  conv_fr_k<16><<<dim3(64, 4), blk, 0, stream>>>(tmp4, nullptr, 1, fr_w2, fr_b2, frbuf);

  for (int b = 0; b < BATCH; ++b) {
    pack_k<<<dim3(9 * HW / 256), blk, 0, stream>>>(feat1, feat2, corr, frbuf, comb, b);

    for (int p = 0; p < 2; ++p) {
      float* ooff = (p ? o_off2 : o_off1) + (size_t)b * 50 * HW;
      float* oww  = (p ? o_w2   : o_w1)   + (size_t)b * 25 * HW;

      convmm_k<0><<<dim3(256, 4), blk, 0, stream>>>(comb, wp1[p], kb1[p], actA,
                                                    nullptr, nullptr, zpage, 288, 256);
      convmm_k<0><<<dim3(256, 4), blk, 0, stream>>>(actA, wp2[p], kb2[p], actB,
                                                    nullptr, nullptr, zpage, 256, 256);
      convmm_k<0><<<dim3(256, 2), blk, 0, stream>>>(actB, wp3[p], kb3[p], actC,
                                                    nullptr, nullptr, zpage, 256, 128);
      convmm_k<1><<<dim3(256, 2), blk, 0, stream>>>(actC, wph[p], hbias[p], nullptr,
                                                    ooff, oww, zpage, 128, 0);
      softmax25_k<<<dim3(HW / 256), blk, 0, stream>>>(oww);
    }

    convmm_k<0><<<dim3(256, 1), blk, 0, stream>>>(comb, wpb, bl_b1, actD,
                                                  nullptr, nullptr, zpage, 288, 64);
    blend2_k<<<dim3(HW / 256), blk, 0, stream>>>(actD, bl_w2, bl_b2, o_blend + (size_t)b * HW);
  }

  adacof_final_k<<<dim3((BATCH * HW + 255) / 256), blk, 0, stream>>>(
      frame1, frame2, o_off1, o_off2, o_w1, o_w2, o_blend, o_out);
}